// Round 3
// baseline (65.683 us; speedup 1.0000x reference)
//
#include <hip/hip_runtime.h>
#include <math.h>

#define BB 32
#define LL 2048
#define DD 256
#define NC 16
#define SPLIT 64      // chunks per batch row
#define TPB 256       // 4 waves
#define TOK_PER_CHUNK (LL / SPLIT)          // 32
#define TOK_PER_WAVE  (TOK_PER_CHUNK / 4)   // 8

// ws layout (floats): emb_sum[BB*DD] | out_unnorm[BB*DD] | ysum[BB] | lens[BB]
#define WS_FLOATS (2 * BB * DD + 2 * BB)

__global__ __launch_bounds__(TPB) void kZero(float* __restrict__ ws) {
  const int i = blockIdx.x * TPB + threadIdx.x;
  if (i < WS_FLOATS) ws[i] = 0.f;
}

__global__ __launch_bounds__(TPB) void kA_embsum(
    const int* __restrict__ idx, const float* __restrict__ mask,
    const float4* __restrict__ enc4,
    float* __restrict__ emb_sum, float* __restrict__ lens) {
  const int b     = blockIdx.x / SPLIT;
  const int chunk = blockIdx.x % SPLIT;
  const int wave  = threadIdx.x >> 6;
  const int lane  = threadIdx.x & 63;
  const int tid   = threadIdx.x;
  const int l0 = chunk * TOK_PER_CHUNK + wave * TOK_PER_WAVE;

  // Prefetch all indices/masks, then issue all gathers back-to-back (8 in flight).
  int   id_r[TOK_PER_WAVE];
  float m_r[TOK_PER_WAVE];
  #pragma unroll
  for (int t = 0; t < TOK_PER_WAVE; ++t) {
    id_r[t] = idx[b * LL + l0 + t];
    m_r[t]  = mask[b * LL + l0 + t];
  }
  float4 v_r[TOK_PER_WAVE];
  #pragma unroll
  for (int t = 0; t < TOK_PER_WAVE; ++t)
    v_r[t] = enc4[(size_t)id_r[t] * (DD / 4) + lane];

  float4 acc = {0.f, 0.f, 0.f, 0.f};
  float lenacc = 0.f;
  #pragma unroll
  for (int t = 0; t < TOK_PER_WAVE; ++t) {
    const float m = m_r[t];
    acc.x += v_r[t].x * m; acc.y += v_r[t].y * m;
    acc.z += v_r[t].z * m; acc.w += v_r[t].w * m;
    lenacc += m;
  }

  __shared__ float lds[4][DD];
  __shared__ float llds[4];
  lds[wave][lane * 4 + 0] = acc.x;
  lds[wave][lane * 4 + 1] = acc.y;
  lds[wave][lane * 4 + 2] = acc.z;
  lds[wave][lane * 4 + 3] = acc.w;
  if (lane == 0) llds[wave] = lenacc;   // lenacc identical across lanes of a wave
  __syncthreads();

  const float s = lds[0][tid] + lds[1][tid] + lds[2][tid] + lds[3][tid];
  atomicAdd(&emb_sum[b * DD + tid], s);
  if (tid == 0) atomicAdd(&lens[b], llds[0] + llds[1] + llds[2] + llds[3]);
}

__global__ __launch_bounds__(TPB) void kB_scores(
    const int* __restrict__ idx, const float* __restrict__ mask,
    const float4* __restrict__ enc4, const float* __restrict__ emb_sum,
    float* __restrict__ out_unnorm, float* __restrict__ ysum) {
  const int b     = blockIdx.x / SPLIT;
  const int chunk = blockIdx.x % SPLIT;
  const int wave  = threadIdx.x >> 6;
  const int lane  = threadIdx.x & 63;
  const int tid   = threadIdx.x;
  const int l0 = chunk * TOK_PER_CHUNK + wave * TOK_PER_WAVE;

  const float4 es = reinterpret_cast<const float4*>(emb_sum)[b * (DD / 4) + lane];

  int   id_r[TOK_PER_WAVE];
  float m_r[TOK_PER_WAVE];
  #pragma unroll
  for (int t = 0; t < TOK_PER_WAVE; ++t) {
    id_r[t] = idx[b * LL + l0 + t];
    m_r[t]  = mask[b * LL + l0 + t];
  }
  float4 v_r[TOK_PER_WAVE];
  #pragma unroll
  for (int t = 0; t < TOK_PER_WAVE; ++t)
    v_r[t] = enc4[(size_t)id_r[t] * (DD / 4) + lane];

  float4 acc = {0.f, 0.f, 0.f, 0.f};
  float ys = 0.f;
  #pragma unroll
  for (int t = 0; t < TOK_PER_WAVE; ++t) {
    const float m = m_r[t];
    const float4 v = v_r[t];
    float d = v.x * es.x + v.y * es.y + v.z * es.z + v.w * es.w;
    // 64-lane butterfly reduce
    #pragma unroll
    for (int off = 32; off > 0; off >>= 1) d += __shfl_xor(d, off);
    const float score = d * m;          // scores = mask * dot(enc_row, emb_sum)
    const float y = expf(score) * m;    // y = exp(scores) * mask
    const float ym = y * m;             // weight on enc row
    acc.x += ym * v.x; acc.y += ym * v.y; acc.z += ym * v.z; acc.w += ym * v.w;
    ys += y;                            // identical across lanes
  }

  __shared__ float lds[4][DD];
  __shared__ float ylds[4];
  lds[wave][lane * 4 + 0] = acc.x;
  lds[wave][lane * 4 + 1] = acc.y;
  lds[wave][lane * 4 + 2] = acc.z;
  lds[wave][lane * 4 + 3] = acc.w;
  if (lane == 0) ylds[wave] = ys;
  __syncthreads();

  const float s = lds[0][tid] + lds[1][tid] + lds[2][tid] + lds[3][tid];
  atomicAdd(&out_unnorm[b * DD + tid], s);
  if (tid == 0) atomicAdd(&ysum[b], ylds[0] + ylds[1] + ylds[2] + ylds[3]);
}

__global__ __launch_bounds__(TPB) void kC_head(
    const float* __restrict__ emb_sum, const float* __restrict__ out_unnorm,
    const float* __restrict__ ysum, const float* __restrict__ lens,
    const float* __restrict__ dec_w, float* __restrict__ out) {
  const int b = blockIdx.x;
  const int tid = threadIdx.x;
  __shared__ float vec[DD];
  vec[tid] = out_unnorm[b * DD + tid] / ysum[b] + emb_sum[b * DD + tid] / lens[b];
  __syncthreads();
  if (tid < NC) {
    float s = 0.f;
    for (int d2 = 0; d2 < DD; ++d2) s += vec[d2] * dec_w[tid * DD + d2];
    out[b * NC + tid] = s;
  }
}

extern "C" void kernel_launch(void* const* d_in, const int* in_sizes, int n_in,
                              void* d_out, int out_size, void* d_ws, size_t ws_size,
                              hipStream_t stream) {
  const int*   idx   = (const int*)d_in[0];
  const float* mask  = (const float*)d_in[1];
  const float* enc_w = (const float*)d_in[2];
  const float* dec_w = (const float*)d_in[3];
  float* out = (float*)d_out;

  float* ws = (float*)d_ws;
  float* emb_sum    = ws;                       // BB*DD
  float* out_unnorm = ws + BB * DD;             // BB*DD
  float* ysum       = ws + 2 * BB * DD;         // BB
  float* lens       = ws + 2 * BB * DD + BB;    // BB

  const dim3 block(TPB);
  hipLaunchKernelGGL(kZero, dim3((WS_FLOATS + TPB - 1) / TPB), block, 0, stream, ws);

  const dim3 grid(BB * SPLIT);
  hipLaunchKernelGGL(kA_embsum, grid, block, 0, stream,
                     idx, mask, (const float4*)enc_w, emb_sum, lens);
  hipLaunchKernelGGL(kB_scores, grid, block, 0, stream,
                     idx, mask, (const float4*)enc_w, emb_sum, out_unnorm, ysum);
  hipLaunchKernelGGL(kC_head, dim3(BB), block, 0, stream,
                     emb_sum, out_unnorm, ysum, lens, dec_w, out);
}

// Round 4
// 33.119 us; speedup vs baseline: 1.9833x; 1.9833x over previous
//
#include <hip/hip_runtime.h>
#include <math.h>

#define BB 32
#define LL 2048
#define DD 256
#define NC 16
#define SPLIT 32      // chunks per batch row
#define TPB 256       // 4 waves
#define TOK_PER_CHUNK (LL / SPLIT)          // 64
#define TOK_PER_WAVE  (TOK_PER_CHUNK / 4)   // 16
#define PF 8          // gathers in flight per wave

// ws layout (floats):
//  pes  [SPLIT][BB][DD]   partial emb_sum        262144
//  plen [SPLIT][BB]       partial lens             1024
//  pout [SPLIT][BB][DD]   partial weighted sum   262144
//  pys  [SPLIT][BB]       partial ysum             1024
//  emb_sum [BB][DD]                                8192
//  lens [BB]                                         32

__global__ __launch_bounds__(TPB) void kA_partial(
    const int* __restrict__ idx, const float* __restrict__ mask,
    const float4* __restrict__ enc4,
    float* __restrict__ pes, float* __restrict__ plen) {
  const int b     = blockIdx.x / SPLIT;
  const int chunk = blockIdx.x % SPLIT;
  const int wave  = threadIdx.x >> 6;
  const int lane  = threadIdx.x & 63;
  const int tid   = threadIdx.x;
  const int l0 = chunk * TOK_PER_CHUNK + wave * TOK_PER_WAVE;

  int   id_r[TOK_PER_WAVE];
  float m_r[TOK_PER_WAVE];
  #pragma unroll
  for (int t = 0; t < TOK_PER_WAVE; ++t) {
    id_r[t] = idx[b * LL + l0 + t];
    m_r[t]  = mask[b * LL + l0 + t];
  }

  float4 acc = {0.f, 0.f, 0.f, 0.f};
  float lenacc = 0.f;
  #pragma unroll
  for (int g = 0; g < TOK_PER_WAVE; g += PF) {
    float4 v[PF];
    #pragma unroll
    for (int t = 0; t < PF; ++t)
      v[t] = enc4[(size_t)id_r[g + t] * (DD / 4) + lane];
    #pragma unroll
    for (int t = 0; t < PF; ++t) {
      const float m = m_r[g + t];
      acc.x += v[t].x * m; acc.y += v[t].y * m;
      acc.z += v[t].z * m; acc.w += v[t].w * m;
      lenacc += m;
    }
  }

  __shared__ float lds[4][DD];
  __shared__ float llds[4];
  lds[wave][lane * 4 + 0] = acc.x;
  lds[wave][lane * 4 + 1] = acc.y;
  lds[wave][lane * 4 + 2] = acc.z;
  lds[wave][lane * 4 + 3] = acc.w;
  if (lane == 0) llds[wave] = lenacc;
  __syncthreads();

  const float s = lds[0][tid] + lds[1][tid] + lds[2][tid] + lds[3][tid];
  pes[(chunk * BB + b) * DD + tid] = s;                 // plain store, no atomics
  if (tid == 0) plen[chunk * BB + b] = llds[0] + llds[1] + llds[2] + llds[3];
}

__global__ __launch_bounds__(TPB) void kR1(
    const float* __restrict__ pes, const float* __restrict__ plen,
    float* __restrict__ emb_sum, float* __restrict__ lens) {
  const int b = blockIdx.x;
  const int tid = threadIdx.x;
  float s = 0.f;
  #pragma unroll
  for (int c = 0; c < SPLIT; ++c) s += pes[(c * BB + b) * DD + tid];
  emb_sum[b * DD + tid] = s;
  if (tid < 64) {
    float v = (tid < SPLIT) ? plen[tid * BB + b] : 0.f;
    #pragma unroll
    for (int off = 16; off > 0; off >>= 1) v += __shfl_xor(v, off);
    if (tid == 0) lens[b] = v;
  }
}

__global__ __launch_bounds__(TPB) void kB_partial(
    const int* __restrict__ idx, const float* __restrict__ mask,
    const float4* __restrict__ enc4, const float* __restrict__ emb_sum,
    float* __restrict__ pout, float* __restrict__ pys) {
  const int b     = blockIdx.x / SPLIT;
  const int chunk = blockIdx.x % SPLIT;
  const int wave  = threadIdx.x >> 6;
  const int lane  = threadIdx.x & 63;
  const int tid   = threadIdx.x;
  const int l0 = chunk * TOK_PER_CHUNK + wave * TOK_PER_WAVE;

  const float4 es = reinterpret_cast<const float4*>(emb_sum)[b * (DD / 4) + lane];

  int   id_r[TOK_PER_WAVE];
  float m_r[TOK_PER_WAVE];
  #pragma unroll
  for (int t = 0; t < TOK_PER_WAVE; ++t) {
    id_r[t] = idx[b * LL + l0 + t];
    m_r[t]  = mask[b * LL + l0 + t];
  }

  float4 acc = {0.f, 0.f, 0.f, 0.f};
  float ys = 0.f;
  #pragma unroll
  for (int g = 0; g < TOK_PER_WAVE; g += PF) {
    float4 v[PF];
    #pragma unroll
    for (int t = 0; t < PF; ++t)
      v[t] = enc4[(size_t)id_r[g + t] * (DD / 4) + lane];
    #pragma unroll
    for (int t = 0; t < PF; ++t) {
      const float m = m_r[g + t];
      float d = v[t].x * es.x + v[t].y * es.y + v[t].z * es.z + v[t].w * es.w;
      #pragma unroll
      for (int off = 32; off > 0; off >>= 1) d += __shfl_xor(d, off);
      const float score = d * m;        // emb_l . emb_sum  (emb_l = m*v)
      const float y = expf(score) * m;  // y = exp(scores) * mask
      const float ym = y * m;           // weight applied to raw enc row
      acc.x += ym * v[t].x; acc.y += ym * v[t].y;
      acc.z += ym * v[t].z; acc.w += ym * v[t].w;
      ys += y;                          // identical across lanes
    }
  }

  __shared__ float lds[4][DD];
  __shared__ float ylds[4];
  lds[wave][lane * 4 + 0] = acc.x;
  lds[wave][lane * 4 + 1] = acc.y;
  lds[wave][lane * 4 + 2] = acc.z;
  lds[wave][lane * 4 + 3] = acc.w;
  if (lane == 0) ylds[wave] = ys;
  __syncthreads();

  const float s = lds[0][tid] + lds[1][tid] + lds[2][tid] + lds[3][tid];
  pout[(chunk * BB + b) * DD + tid] = s;
  if (tid == 0) pys[chunk * BB + b] = ylds[0] + ylds[1] + ylds[2] + ylds[3];
}

__global__ __launch_bounds__(TPB) void kR2head(
    const float* __restrict__ pout, const float* __restrict__ pys,
    const float* __restrict__ emb_sum, const float* __restrict__ lens,
    const float* __restrict__ dec_w, float* __restrict__ out) {
  const int b = blockIdx.x;
  const int tid = threadIdx.x;
  const int wave = tid >> 6;
  const int lane = tid & 63;

  float os = 0.f;
  #pragma unroll
  for (int c = 0; c < SPLIT; ++c) os += pout[(c * BB + b) * DD + tid];

  __shared__ float ysum_s;
  __shared__ float vec[DD];
  if (tid < 64) {
    float v = (tid < SPLIT) ? pys[tid * BB + b] : 0.f;
    #pragma unroll
    for (int off = 16; off > 0; off >>= 1) v += __shfl_xor(v, off);
    if (tid == 0) ysum_s = v;
  }
  __syncthreads();

  vec[tid] = os / ysum_s + emb_sum[b * DD + tid] / lens[b];
  __syncthreads();

  // head: wave w computes classes 4w .. 4w+3
  const float4 vv = *reinterpret_cast<const float4*>(&vec[lane * 4]);
  #pragma unroll
  for (int cc = 0; cc < 4; ++cc) {
    const int c = wave * 4 + cc;
    const float4 dw = reinterpret_cast<const float4*>(dec_w)[c * (DD / 4) + lane];
    float d = vv.x * dw.x + vv.y * dw.y + vv.z * dw.z + vv.w * dw.w;
    #pragma unroll
    for (int off = 32; off > 0; off >>= 1) d += __shfl_xor(d, off);
    if (lane == 0) out[b * NC + c] = d;
  }
}

extern "C" void kernel_launch(void* const* d_in, const int* in_sizes, int n_in,
                              void* d_out, int out_size, void* d_ws, size_t ws_size,
                              hipStream_t stream) {
  const int*   idx   = (const int*)d_in[0];
  const float* mask  = (const float*)d_in[1];
  const float* enc_w = (const float*)d_in[2];
  const float* dec_w = (const float*)d_in[3];
  float* out = (float*)d_out;

  float* ws = (float*)d_ws;
  float* pes     = ws;                                   // SPLIT*BB*DD
  float* plen    = pes + SPLIT * BB * DD;                // SPLIT*BB
  float* pout    = plen + SPLIT * BB;                    // SPLIT*BB*DD
  float* pys     = pout + SPLIT * BB * DD;               // SPLIT*BB
  float* emb_sum = pys + SPLIT * BB;                     // BB*DD
  float* lens    = emb_sum + BB * DD;                    // BB

  const dim3 block(TPB);
  const dim3 gridP(BB * SPLIT);
  hipLaunchKernelGGL(kA_partial, gridP, block, 0, stream,
                     idx, mask, (const float4*)enc_w, pes, plen);
  hipLaunchKernelGGL(kR1, dim3(BB), block, 0, stream, pes, plen, emb_sum, lens);
  hipLaunchKernelGGL(kB_partial, gridP, block, 0, stream,
                     idx, mask, (const float4*)enc_w, emb_sum, pout, pys);
  hipLaunchKernelGGL(kR2head, dim3(BB), block, 0, stream,
                     pout, pys, emb_sum, lens, dec_w, out);
}